// Round 1
// 123.209 us; speedup vs baseline: 1.0605x; 1.0605x over previous
//
#include <hip/hip_runtime.h>
#include <float.h>
#include <math.h>
#include <stdint.h>

// VQ-VAE VectorQuantizer — round 3: code-split waves, L2-streamed A-frags,
// barrier-free MFMA main loop.
//
// z_e: (32, 256, 32, 32) fp32, weight: (1024, 256) fp32
// outputs concat: quantized_st (8388608) + loss (1) + perplexity (1)
//
// score[k][n] = wsq[k] - 2*w_k.z_n  via  mfma_f32_16x16x32_bf16:
//   A (M=16 codes)  = -2*w  (bf16, packed in A-frag order by vq_prep)
//   B (N=16 z vecs) =  z    (bf16, register-resident, 4 N-tiles = 64 z/wave)
//   C init          =  wsq[k]
//
// Main-kernel decomposition: 512 blocks x 256 thr (4 waves).
//   block  -> 64 z vectors (b = bid>>4, hw0 = (bid&15)*64)
//   wave w -> code quarter [w*256, w*256+256), sweeps its 16 A-tiles from
//             GLOBAL (L2-resident 512 KB cbfrag; read exactly once per wave,
//             1 KB/instr coalesced). No LDS staging, no __syncthreads in loop.
//
// ws layout (bytes): [0,4096) wsq f32 | [4096,8192) counts u32
//                    [8192,8196) loss_sum f32 | [16384, 16384+524288) cbfrag

#define NB   32
#define NC   256
#define NHW  1024
#define NK   1024
#define NELEM (NB*NC*NHW)   // 8388608

typedef __attribute__((ext_vector_type(8))) short bf16x8;   // 8 bf16 = 4 VGPRs
typedef __attribute__((ext_vector_type(4))) float f32x4;

__device__ __forceinline__ unsigned short f2bf(float f) {   // RTN fp32->bf16
    unsigned u = __float_as_uint(f);
    u += 0x7FFFu + ((u >> 16) & 1u);
    return (unsigned short)(u >> 16);
}

// ---------------- K1: prep — pack A-frags (-2w bf16) + wsq + zero accums ---
// grid 64 x 256. Block t packs code tile-set t (16 codes) and computes their
// squared norms from the same loaded values. Block 0 zeroes counts/loss.
__global__ __launch_bounds__(256) void vq_prep(const float* __restrict__ w,
                                               unsigned short* __restrict__ cb,
                                               float* __restrict__ wsq,
                                               unsigned int* __restrict__ counts,
                                               float* __restrict__ loss_sum) {
    __shared__ float swsq[4][16];
    const int t   = blockIdx.x;          // code tile 0..63 (16 codes each)
    const int tid = threadIdx.x;
    float sq = 0.f;
#pragma unroll
    for (int rep = 0; rep < 2; ++rep) {
        const int p = tid + rep * 256;   // 0..511
        const int cc = p >> 6, l = p & 63;
        const int n = l & 15, quad = l >> 4;
        const float* src = w + (t * 16 + n) * NC + cc * 32 + quad * 8;
        const float4 f0 = *(const float4*)src;
        const float4 f1 = *(const float4*)(src + 4);
        union { unsigned short u[8]; uint4 v; } pk;
        pk.u[0] = f2bf(-2.f * f0.x); pk.u[1] = f2bf(-2.f * f0.y);
        pk.u[2] = f2bf(-2.f * f0.z); pk.u[3] = f2bf(-2.f * f0.w);
        pk.u[4] = f2bf(-2.f * f1.x); pk.u[5] = f2bf(-2.f * f1.y);
        pk.u[6] = f2bf(-2.f * f1.z); pk.u[7] = f2bf(-2.f * f1.w);
        *(uint4*)(cb + (size_t)t * 4096 + cc * 512 + l * 8) = pk.v;
        sq = fmaf(f0.x, f0.x, sq); sq = fmaf(f0.y, f0.y, sq);
        sq = fmaf(f0.z, f0.z, sq); sq = fmaf(f0.w, f0.w, sq);
        sq = fmaf(f1.x, f1.x, sq); sq = fmaf(f1.y, f1.y, sq);
        sq = fmaf(f1.z, f1.z, sq); sq = fmaf(f1.w, f1.w, sq);
    }
    // fold quad dimension (lanes n, n+16, n+32, n+48 share row n)
    sq += __shfl_xor(sq, 16, 64);
    sq += __shfl_xor(sq, 32, 64);
    const int wv = tid >> 6, lane = tid & 63;
    if (lane < 16) swsq[wv][lane] = sq;
    __syncthreads();
    if (tid < 16)
        wsq[t * 16 + tid] = swsq[0][tid] + swsq[1][tid] + swsq[2][tid] + swsq[3][tid];
    if (t == 0) {
        for (int i = tid; i < NK; i += 256) counts[i] = 0u;
        if (tid == 0) loss_sum[0] = 0.f;
    }
}

// ---------------- K2: main — barrier-free MFMA argmin + gather + loss ------
__global__ __launch_bounds__(256, 2) void vq_main3(const float* __restrict__ z,
                                                   const float* __restrict__ w,
                                                   const float* __restrict__ wsq,
                                                   const unsigned short* __restrict__ cb,
                                                   unsigned int* __restrict__ counts,
                                                   float* __restrict__ loss_sum,
                                                   float* __restrict__ out) {
    __shared__ float sval[4][64];
    __shared__ int   sidx[4][64];
    __shared__ int   fidx[64];
    __shared__ float lred[4];

    const int tid  = threadIdx.x;
    const int wv   = tid >> 6;            // code quarter 0..3
    const int lane = tid & 63;
    const int n    = lane & 15;
    const int quad = lane >> 4;
    const int bid  = blockIdx.x;
    const int b    = bid >> 4;            // batch image
    const int hw0  = (bid & 15) << 6;     // block's 64-row hw origin

    const float* zb = z + (size_t)b * (NC * NHW);

    // ---- Phase A: 64 z vectors -> register B-fragments (bf16), 128 VGPRs --
    bf16x8 bfr[4][8];
#pragma unroll
    for (int nt = 0; nt < 4; ++nt) {
#pragma unroll
        for (int cc = 0; cc < 8; ++cc) {
            const float* zp = zb + (size_t)(cc * 32 + quad * 8) * NHW + hw0 + nt * 16 + n;
            union { unsigned short u[8]; bf16x8 v; } pk;
#pragma unroll
            for (int j = 0; j < 8; ++j) pk.u[j] = f2bf(zp[(size_t)j * NHW]);
            bfr[nt][cc] = pk.v;
        }
    }

    // ---- Main loop: wave sweeps its 16 code tiles straight from L2 --------
    float bv[4] = {FLT_MAX, FLT_MAX, FLT_MAX, FLT_MAX};
    int   bi[4] = {0, 0, 0, 0};
    const unsigned short* ap0 = cb + (size_t)(wv * 16) * 4096 + lane * 8;

    for (int mt = 0; mt < 16; ++mt) {
        const int kt = wv * 256 + mt * 16;
        const unsigned short* ap = ap0 + (size_t)mt * 4096;
        const f32x4 w4 = *(const f32x4*)(wsq + kt + quad * 4);
        f32x4 acc[4];
#pragma unroll
        for (int nt = 0; nt < 4; ++nt) acc[nt] = w4;
#pragma unroll
        for (int cc = 0; cc < 8; ++cc) {
            const bf16x8 af = *(const bf16x8*)(ap + cc * 512);
            acc[0] = __builtin_amdgcn_mfma_f32_16x16x32_bf16(af, bfr[0][cc], acc[0], 0, 0, 0);
            acc[1] = __builtin_amdgcn_mfma_f32_16x16x32_bf16(af, bfr[1][cc], acc[1], 0, 0, 0);
            acc[2] = __builtin_amdgcn_mfma_f32_16x16x32_bf16(af, bfr[2][cc], acc[2], 0, 0, 0);
            acc[3] = __builtin_amdgcn_mfma_f32_16x16x32_bf16(af, bfr[3][cc], acc[3], 0, 0, 0);
        }
#pragma unroll
        for (int nt = 0; nt < 4; ++nt) {
#pragma unroll
            for (int r = 0; r < 4; ++r) {
                const float v = acc[nt][r];
                if (v < bv[nt]) { bv[nt] = v; bi[nt] = kt + quad * 4 + r; }
            }
        }
    }

    // ---- cross-quad argmin (lanes n, n+16, n+32, n+48) --------------------
#pragma unroll
    for (int nt = 0; nt < 4; ++nt) {
#pragma unroll
        for (int off = 16; off <= 32; off <<= 1) {
            const float ov = __shfl_xor(bv[nt], off, 64);
            const int   ok = __shfl_xor(bi[nt], off, 64);
            if (ov < bv[nt] || (ov == bv[nt] && ok < bi[nt])) { bv[nt] = ov; bi[nt] = ok; }
        }
    }
    if (lane < 16) {
#pragma unroll
        for (int nt = 0; nt < 4; ++nt) {
            sval[wv][nt * 16 + lane] = bv[nt];
            sidx[wv][nt * 16 + lane] = bi[nt];
        }
    }
    __syncthreads();

    // ---- cross-wave argmin over the 4 code quarters (ascending => lowest) -
    if (tid < 64) {
        float bestv = sval[0][tid];
        int   besti = sidx[0][tid];
#pragma unroll
        for (int q = 1; q < 4; ++q) {
            const float v = sval[q][tid];
            const int   k = sidx[q][tid];
            if (v < bestv || (v == bestv && k < besti)) { bestv = v; besti = k; }
        }
        fidx[tid] = besti;
        atomicAdd(&counts[besti], 1u);
    }
    __syncthreads();

    // ---- Phase 2: gather codebook rows, write quantized, accumulate loss --
    float lsum = 0.f;
    const int hwl = tid & 63;
    const int cg  = tid >> 6;             // 0..3 -> c range [cg*64, cg*64+64)
    const int myk = fidx[hwl];
    const float* wr  = w + myk * NC;
    const float* zp2 = zb + hw0 + hwl;
    float*       op  = out + (size_t)b * (NC * NHW) + hw0 + hwl;
#pragma unroll 4
    for (int p = 0; p < 16; ++p) {
        const int c0 = cg * 64 + p * 4;
        const float4 q4 = *(const float4*)(wr + c0);
        const float qa[4] = {q4.x, q4.y, q4.z, q4.w};
#pragma unroll
        for (int u = 0; u < 4; ++u) {
            const int c = c0 + u;
            const float zv = zp2[(size_t)c * NHW];
            const float d = qa[u] - zv;
            lsum = fmaf(d, d, lsum);
            op[(size_t)c * NHW] = qa[u];
        }
    }
#pragma unroll
    for (int off = 32; off; off >>= 1) lsum += __shfl_down(lsum, off, 64);
    if (lane == 0) lred[wv] = lsum;
    __syncthreads();
    if (tid == 0)
        atomicAdd(loss_sum, lred[0] + lred[1] + lred[2] + lred[3]);
}

// ---------------- K3: finalize loss + perplexity ----------------
__global__ __launch_bounds__(256) void vq_final(const unsigned int* __restrict__ counts,
                                                const float* __restrict__ loss_sum,
                                                float* __restrict__ out) {
    __shared__ float red[4];
    const int tid = threadIdx.x;
    float s = 0.f;
#pragma unroll
    for (int p = 0; p < 4; ++p) {
        const float pr = (float)counts[tid + p * 256] * (1.f / 32768.f);
        s = fmaf(pr, logf(pr + 1e-10f), s);
    }
#pragma unroll
    for (int off = 32; off; off >>= 1) s += __shfl_down(s, off, 64);
    if ((tid & 63) == 0) red[tid >> 6] = s;
    __syncthreads();
    if (tid == 0) {
        const float tot = red[0] + red[1] + red[2] + red[3];
        out[NELEM]     = loss_sum[0] * (1.25f / (float)NELEM);
        out[NELEM + 1] = expf(-tot);
    }
}

extern "C" void kernel_launch(void* const* d_in, const int* in_sizes, int n_in,
                              void* d_out, int out_size, void* d_ws, size_t ws_size,
                              hipStream_t stream) {
    const float* z = (const float*)d_in[0];
    const float* w = (const float*)d_in[1];
    float* out = (float*)d_out;

    float*          wsq      = (float*)d_ws;
    unsigned int*   counts   = (unsigned int*)((char*)d_ws + 4096);
    float*          loss_sum = (float*)((char*)d_ws + 8192);
    unsigned short* cbfrag   = (unsigned short*)((char*)d_ws + 16384);  // 512 KB

    vq_prep <<<64,  256, 0, stream>>>(w, cbfrag, wsq, counts, loss_sum);
    vq_main3<<<512, 256, 0, stream>>>(z, w, wsq, cbfrag, counts, loss_sum, out);
    vq_final<<<1,   256, 0, stream>>>(counts, loss_sum, out);
}